// Round 10
// baseline (344.921 us; speedup 1.0000x reference)
//
#include <hip/hip_runtime.h>

// B=4, L=64, C=64, H=W=32, K=3, CONN=4
#define NIMG 256
#define CCH 64
#define HWSZ 1024
#define IMG_NHWC 65536            // 1024 px * 64 c (bf16 elements per image)

typedef __attribute__((ext_vector_type(8))) short  s16x8;
typedef __attribute__((ext_vector_type(4))) short  s16x4;
typedef __attribute__((ext_vector_type(4))) float  f32x4;

__device__ __forceinline__ unsigned short f2bf(float f) {
    unsigned u = __builtin_bit_cast(unsigned, f);
    u += 0x7fffu + ((u >> 16) & 1u);          // RNE
    return (unsigned short)(u >> 16);
}
__device__ __forceinline__ float bf2f(unsigned short h) {
    unsigned u = ((unsigned)h) << 16;
    return __builtin_bit_cast(float, u);
}

// async global->LDS, 16B per lane. LDS dest = wave-uniform base + lane*16 (m104).
__device__ __forceinline__ void gload_lds16(const void* g, void* l) {
    __builtin_amdgcn_global_load_lds(
        (const __attribute__((address_space(1))) unsigned int*)g,
        (__attribute__((address_space(3))) unsigned int*)l, 16, 0, 0);
}

// ---------------------------------------------------------------------------
// pack weights (blocks 0..575) + build nbr list (block 576). Weight layout:
// [conv][tap][co][sp][8] bf16 with sp = slot^(co&7) pre-applied (r7/r9-proven:
// linear gload_lds staging + XOR'd ds_read -> conflict-balanced).
// ---------------------------------------------------------------------------
__global__ __launch_bounds__(256) void pack_build_kernel(const float* __restrict__ w0,
                                                         const float* __restrict__ w1,
                                                         const float* __restrict__ w2,
                                                         const float* __restrict__ w3,
                                                         unsigned short* __restrict__ wp,
                                                         const unsigned char* __restrict__ mraw,
                                                         int* __restrict__ nbr) {
    if (blockIdx.x == 576) {   // build_nbr (validated R2)
        __shared__ int nz;
        int t = threadIdx.x;
        if (t == 0) nz = 0;
        __syncthreads();
        int local = 0;
        for (int i = t; i < 16384; i += 256) local += (mraw[i] != 0) ? 1 : 0;
        atomicAdd(&nz, local);
        __syncthreads();
        bool isByte = (nz == 1024);
        const int* mi = (const int*)mraw;
        int c = 0;
        int base = t * 64;
        for (int j = 0; j < 64; ++j) {
            int v = isByte ? (int)mraw[base + j] : mi[base + j];
            if (v != 0 && c < 4) { nbr[t * 4 + c] = j; ++c; }
        }
        for (; c < 4; ++c) nbr[t * 4 + c] = -1;
        return;
    }
    int idx = blockIdx.x * 256 + threadIdx.x;      // 4*9*64*64 = 147456
    int e  = idx & 7;
    int sp = (idx >> 3) & 7;
    int co = (idx >> 6) & 63;
    int tc = idx >> 12;                            // cv*9 + tap
    int cv = tc / 9, tap = tc - cv * 9;
    int ci = ((sp ^ (co & 7)) << 3) + e;           // logical slot stored at sp
    const float* w = (cv == 0) ? w0 : (cv == 1) ? w1 : (cv == 2) ? w2 : w3;
    wp[idx] = f2bf(w[(co * 64 + ci) * 9 + tap]);
}

// ---------------------------------------------------------------------------
// NCHW f32 -> NHWC bf16, LDS-tiled transpose. Block = quarter image (256 px).
// ---------------------------------------------------------------------------
__global__ __launch_bounds__(256) void to_nhwc_kernel(const float* __restrict__ x,
                                                      unsigned short* __restrict__ xb) {
    __shared__ unsigned short lds[256 * 68];
    int bid = blockIdx.x;                 // 1024
    int n = bid >> 2, px0 = (bid & 3) * 256;
    int t = threadIdx.x, w = t >> 6, l = t & 63;

    #pragma unroll
    for (int pp = 0; pp < 8; ++pp) {      // channel pairs per wave
        int c = w * 16 + pp * 2;
        const float* s0 = x + ((size_t)(n * 64 + c)) * HWSZ + px0;
        const float* s1 = s0 + HWSZ;
        #pragma unroll
        for (int ch = 0; ch < 4; ++ch) {
            int px = ch * 64 + l;
            unsigned pack = (unsigned)f2bf(s0[px]) | ((unsigned)f2bf(s1[px]) << 16);
            *(unsigned*)((char*)lds + px * 136 + c * 2) = pack;
        }
    }
    __syncthreads();
    #pragma unroll
    for (int it = 0; it < 8; ++it) {
        int pos = it * 256 + t;
        int px = pos >> 3, c0 = (pos & 7) * 8;
        const char* src = (const char*)lds + px * 136 + c0 * 2;
        s16x4 v0 = *(const s16x4*)src;
        s16x4 v1 = *(const s16x4*)(src + 8);
        unsigned short* dst = xb + ((size_t)(n * 1024) + px0 + px) * 64 + c0;
        *(s16x4*)dst = v0;
        *(s16x4*)(dst + 4) = v1;
    }
}

// ---------------------------------------------------------------------------
// CONV-PAIR kernel (r10): both convs of one layer in ONE dispatch.
// grid 1024: bid -> n=bid>>2, half=(bid>>1)&1, sel=bid&1 (consecutive blocks
// share the input tile -> L2-hot second stage).
// Block = image-half (16 rows): tile [18 rows][34 cols][64 ci] = 78336 B +
// full weights 73728 B = 152 KB -> 1 block/CU. ONE barrier, no stripe loop.
// Wave = 4 rows x 32 px x 64 co: acc[4m][8p] (128 VGPR) -> A-reads halved
// vs r9 (amortized over 8 px-positions). Swizzles r9-verbatim.
// ---------------------------------------------------------------------------
__global__ __launch_bounds__(256, 1) void conv_pair_kernel(const unsigned short* __restrict__ act,
                                                           const unsigned short* __restrict__ wpA,
                                                           const unsigned short* __restrict__ wpB,
                                                           const float* __restrict__ bA,
                                                           const float* __restrict__ bB,
                                                           unsigned short* __restrict__ outA,
                                                           unsigned short* __restrict__ outB) {
    __shared__ unsigned short wlds[36864];          // 73728 B [tap][co][sp][8]
    __shared__ unsigned short tile[18 * 34 * 64];   // 78336 B
    int bid = blockIdx.x;                           // 1024
    int n = bid >> 2, half = (bid >> 1) & 1, sel = bid & 1;
    const unsigned short* wconv = sel ? wpB : wpA;
    const float* bias = sel ? bB : bA;
    unsigned short* outp = sel ? outB : outA;
    int y0 = half * 16;
    int t = threadIdx.x, w = t >> 6, l = t & 63;

    // ---- prologue: weights (18 x 4KB) + input rows (18 x 4KB) + pad cols ----
    #pragma unroll
    for (int j = 0; j < 18; ++j) {
        int off = j * 4096 + w * 1024;              // wave-uniform byte offset
        gload_lds16((const char*)wconv + off + l * 16, (char*)wlds + off);
    }
    {
        const unsigned short* img = act + ((size_t)n << 16);
        int x1 = (t >> 3) & 31, slot = t & 7;
        int c = x1 + 1;
        int sslot = slot ^ (c & 7);                 // pre-swizzled global source
        char* base = (char*)tile + 128 + w * 1024;  // wave-uniform (col-1 start)
        #pragma unroll
        for (int r = 0; r < 18; ++r) {
            int y = y0 - 1 + r;
            if (y >= 0 && y < 32) {                 // block-uniform branch
                gload_lds16(img + (y * 32 + x1) * 64 + sslot * 8, base + r * 4352);
            } else {
                s16x8 z = {0,0,0,0,0,0,0,0};
                *(s16x8*)((char*)tile + r * 4352 + c * 128 + slot * 16) = z;
            }
        }
        #pragma unroll
        for (int k = 0; k < 2; ++k) {               // pad cols 0,33 (18 rows)
            int idx = k * 256 + t;
            if (idx < 288) {
                int r = idx >> 4, cp = ((idx >> 3) & 1) ? 33 : 0, sl = idx & 7;
                s16x8 z = {0,0,0,0,0,0,0,0};
                int off = ((r * 34 + cp) * 128 + sl * 16) ^ ((cp & 7) << 4);
                *(s16x8*)((char*)tile + off) = z;
            }
        }
    }
    __syncthreads();

    int lm = l & 15, kg = l >> 4;
    f32x4 acc[4][8];
    #pragma unroll
    for (int m = 0; m < 4; ++m)
        #pragma unroll
        for (int p = 0; p < 8; ++p) acc[m][p] = (f32x4){0.f, 0.f, 0.f, 0.f};

    #pragma unroll
    for (int tap = 0; tap < 9; ++tap) {
        const int dy = tap / 3, dx = tap % 3;
        #pragma unroll
        for (int g = 0; g < 2; ++g) {
            s16x8 a[4];
            #pragma unroll
            for (int m = 0; m < 4; ++m) {
                int row = m * 16 + lm;
                int ao  = tap * 8192 + row * 128 + (((g * 4 + kg) ^ (lm & 7)) * 16);
                a[m] = *(const s16x8*)((const char*)wlds + ao);
            }
            #pragma unroll
            for (int rl = 0; rl < 4; ++rl) {
                int r = 4 * w + rl + dy;            // 0..17
                s16x8 b0, b1;
                {
                    int xl = lm + dx;
                    int lb = (r * 4352 + xl * 128 + g * 64 + kg * 16) ^ ((xl & 7) << 4);
                    b0 = *(const s16x8*)((const char*)tile + lb);
                }
                {
                    int xl = 16 + lm + dx;
                    int lb = (r * 4352 + xl * 128 + g * 64 + kg * 16) ^ ((xl & 7) << 4);
                    b1 = *(const s16x8*)((const char*)tile + lb);
                }
                #pragma unroll
                for (int m = 0; m < 4; ++m) {
                    acc[m][rl * 2 + 0] = __builtin_amdgcn_mfma_f32_16x16x32_bf16(a[m], b0, acc[m][rl * 2 + 0], 0, 0, 0);
                    acc[m][rl * 2 + 1] = __builtin_amdgcn_mfma_f32_16x16x32_bf16(a[m], b1, acc[m][rl * 2 + 1], 0, 0, 0);
                }
            }
        }
    }

    // ---- bias + store NHWC bf16. D: col(px)=lane&15, row(co)=kg*4+reg (m89) ----
    #pragma unroll
    for (int m = 0; m < 4; ++m) {
        f32x4 bv = *(const f32x4*)(bias + m * 16 + kg * 4);
        #pragma unroll
        for (int rl = 0; rl < 4; ++rl) {
            int y = y0 + 4 * w + rl;
            #pragma unroll
            for (int ph = 0; ph < 2; ++ph) {
                int xx = ph * 16 + lm;
                s16x4 o;
                #pragma unroll
                for (int j = 0; j < 4; ++j) o[j] = (short)f2bf(acc[m][rl * 2 + ph][j] + bv[j]);
                *(s16x4*)(outp + (((size_t)n * 1024 + y * 32 + xx) * 64) + m * 16 + kg * 4) = o;
            }
        }
    }
}

// ---------------------------------------------------------------------------
// READ-ONCE aggregate: h = relu(hx + sum_k nset[nbr_k]) in place.
// Block = (batch, 512-feature slice): stage slice for ALL 64 images in LDS
// (65-unit padded rows -> banks spread by j%8), each output row sums 4
// neighbors from LDS. nset read ONCE (32MB) instead of 4x gather (128MB).
// ---------------------------------------------------------------------------
__global__ __launch_bounds__(256, 2) void agg_relu2_kernel(unsigned short* __restrict__ hx,
                                                           const unsigned short* __restrict__ nset,
                                                           const int* __restrict__ nbr) {
    __shared__ unsigned short lds[64 * 65 * 8];     // 66560 B
    int bid = blockIdx.x;                           // 512
    int b = bid >> 7, sl = bid & 127;
    size_t base_e = (size_t)sl * 512;
    int t = threadIdx.x, w = t >> 6, l = t & 63;

    #pragma unroll
    for (int k = 0; k < 16; ++k) {                  // wave w stages rows w*16..+15
        int j = w * 16 + k;
        gload_lds16(nset + (((size_t)(b * 64 + j)) << 16) + base_e + l * 8,
                    (char*)lds + j * 1040 + l * 16);
    }
    __syncthreads();

    int i = t >> 2, q = t & 3;
    int j0 = nbr[(b * 64 + i) * 4 + 0];
    int j1 = nbr[(b * 64 + i) * 4 + 1];
    int j2 = nbr[(b * 64 + i) * 4 + 2];
    int j3 = nbr[(b * 64 + i) * 4 + 3];
    unsigned short* row = hx + (((size_t)(b * 64 + i)) << 16) + base_e + q * 128;
    #pragma unroll
    for (int u = 0; u < 16; ++u) {
        int e = q * 16 + u;
        s16x8 hv = *(const s16x8*)(row + u * 8);
        float s[8];
        #pragma unroll
        for (int j = 0; j < 8; ++j) s[j] = bf2f((unsigned short)hv[j]);
        if (j0 >= 0) { s16x8 nv = *(const s16x8*)((const char*)lds + (j0 * 65 + e) * 16);
            #pragma unroll
            for (int j = 0; j < 8; ++j) s[j] += bf2f((unsigned short)nv[j]); }
        if (j1 >= 0) { s16x8 nv = *(const s16x8*)((const char*)lds + (j1 * 65 + e) * 16);
            #pragma unroll
            for (int j = 0; j < 8; ++j) s[j] += bf2f((unsigned short)nv[j]); }
        if (j2 >= 0) { s16x8 nv = *(const s16x8*)((const char*)lds + (j2 * 65 + e) * 16);
            #pragma unroll
            for (int j = 0; j < 8; ++j) s[j] += bf2f((unsigned short)nv[j]); }
        if (j3 >= 0) { s16x8 nv = *(const s16x8*)((const char*)lds + (j3 * 65 + e) * 16);
            #pragma unroll
            for (int j = 0; j < 8; ++j) s[j] += bf2f((unsigned short)nv[j]); }
        s16x8 o;
        #pragma unroll
        for (int j = 0; j < 8; ++j) o[j] = (short)f2bf(fmaxf(s[j], 0.f));
        *(s16x8*)(row + u * 8) = o;
    }
}

// ---------------------------------------------------------------------------
// out = relu(h2x + sum_k nset[nbr_k] + xb), NHWC bf16 -> NCHW f32 via LDS.
// Residual from xb (bf16 NHWC, phase-A add) - saves the 64MB f32 x re-read.
// ---------------------------------------------------------------------------
__global__ __launch_bounds__(256) void final_kernel(const unsigned short* __restrict__ h2x,
                                                    const unsigned short* __restrict__ nset,
                                                    const int* __restrict__ nbr,
                                                    const unsigned short* __restrict__ xb,
                                                    float* __restrict__ out) {
    __shared__ float lds[128 * 68];
    int bid = blockIdx.x;                          // 2048
    int n = bid >> 3, px0 = (bid & 7) * 128;
    int b = n >> 6;
    int t = threadIdx.x;
    int j0 = nbr[n * 4 + 0], j1 = nbr[n * 4 + 1], j2 = nbr[n * 4 + 2], j3 = nbr[n * 4 + 3];
    size_t base = ((size_t)n * 1024 + px0) * 64;
    size_t nb[4];
    nb[0] = ((size_t)(b * 64 + (j0 < 0 ? 0 : j0)) * 1024 + px0) * 64;
    nb[1] = ((size_t)(b * 64 + (j1 < 0 ? 0 : j1)) * 1024 + px0) * 64;
    nb[2] = ((size_t)(b * 64 + (j2 < 0 ? 0 : j2)) * 1024 + px0) * 64;
    nb[3] = ((size_t)(b * 64 + (j3 < 0 ? 0 : j3)) * 1024 + px0) * 64;
    int use[4] = {j0 >= 0, j1 >= 0, j2 >= 0, j3 >= 0};

    #pragma unroll
    for (int it = 0; it < 4; ++it) {
        int pos = it * 256 + t;
        int px = pos >> 3, c0 = (pos & 7) * 8;
        int off = px * 64 + c0;
        float s[8];
        s16x8 hv = *(const s16x8*)(h2x + base + off);
        s16x8 rv = *(const s16x8*)(xb + base + off);
        #pragma unroll
        for (int j = 0; j < 8; ++j)
            s[j] = bf2f((unsigned short)hv[j]) + bf2f((unsigned short)rv[j]);
        #pragma unroll
        for (int k = 0; k < 4; ++k) {
            if (use[k]) {
                s16x8 nv = *(const s16x8*)(nset + nb[k] + off);
                #pragma unroll
                for (int j = 0; j < 8; ++j) s[j] += bf2f((unsigned short)nv[j]);
            }
        }
        float* dst = &lds[px * 68 + c0];
        *(f32x4*)dst = (f32x4){fmaxf(s[0],0.f), fmaxf(s[1],0.f), fmaxf(s[2],0.f), fmaxf(s[3],0.f)};
        *(f32x4*)(dst + 4) = (f32x4){fmaxf(s[4],0.f), fmaxf(s[5],0.f), fmaxf(s[6],0.f), fmaxf(s[7],0.f)};
    }
    __syncthreads();

    int w = t >> 6, l = t & 63;
    #pragma unroll
    for (int q = 0; q < 4; ++q) {
        int c0 = w * 16 + q * 4;
        #pragma unroll
        for (int half = 0; half < 2; ++half) {
            int px = half * 64 + l;
            f32x4 v = *(const f32x4*)&lds[px * 68 + c0];
            #pragma unroll
            for (int j = 0; j < 4; ++j) {
                size_t a = ((size_t)(n * 64) + c0 + j) * HWSZ + px0 + px;
                out[a] = v[j];
            }
        }
    }
}

// ---------------------------------------------------------------------------
extern "C" void kernel_launch(void* const* d_in, const int* in_sizes, int n_in,
                              void* d_out, int out_size, void* d_ws, size_t ws_size,
                              hipStream_t stream) {
    const float* x    = (const float*)d_in[0];
    const float* w_x0 = (const float*)d_in[1];
    const float* b_x0 = (const float*)d_in[2];
    const float* w_n0 = (const float*)d_in[3];
    const float* b_n0 = (const float*)d_in[4];
    const float* w_x1 = (const float*)d_in[5];
    const float* b_x1 = (const float*)d_in[6];
    const float* w_n1 = (const float*)d_in[7];
    const float* b_n1 = (const float*)d_in[8];
    const unsigned char* mask = (const unsigned char*)d_in[9];

    unsigned short* xb    = (unsigned short*)d_ws;              // x NHWC bf16 (kept for resid)
    unsigned short* hxb   = xb   + (size_t)NIMG * IMG_NHWC;     // hx -> h (in-place agg)
    unsigned short* nsetb = hxb  + (size_t)NIMG * IMG_NHWC;     // n_set (both layers)
    unsigned short* h2xb  = nsetb + (size_t)NIMG * IMG_NHWC;    // h2x
    unsigned short* wpack = h2xb + (size_t)NIMG * IMG_NHWC;     // [4][9][64][64]
    int* nbr = (int*)(wpack + 147456);

    pack_build_kernel<<<577, 256, 0, stream>>>(w_n0, w_x0, w_n1, w_x1, wpack, mask, nbr);
    to_nhwc_kernel<<<1024, 256, 0, stream>>>(x, xb);

    const unsigned short* wp_n0 = wpack;
    const unsigned short* wp_x0 = wpack + 36864;
    const unsigned short* wp_n1 = wpack + 73728;
    const unsigned short* wp_x1 = wpack + 110592;

    // layer 0: one dispatch for both convs, then read-once agg (in place)
    conv_pair_kernel<<<1024, 256, 0, stream>>>(xb, wp_n0, wp_x0, b_n0, b_x0, nsetb, hxb);
    agg_relu2_kernel<<<512, 256, 0, stream>>>(hxb, nsetb, nbr);

    // layer 1: both convs, then fused agg+resid+relu+transpose epilogue
    conv_pair_kernel<<<1024, 256, 0, stream>>>(hxb, wp_n1, wp_x1, b_n1, b_x1, nsetb, h2xb);
    final_kernel<<<2048, 256, 0, stream>>>(h2xb, nsetb, nbr, xb, (float*)d_out);
}